// Round 7
// baseline (6193.741 us; speedup 1.0000x reference)
//
#include <hip/hip_runtime.h>
#include <math.h>

#define NB 8
#define NV 201
#define ND 256
#define NPIX (NB*NV*NV)        // 323208 (full pixel count; BN normalizer)
#define TRI  (NV*(NV+1)/2)     // 20301 upper-triangle pixels per batch (i<=j)
#define NSYM (NB*TRI)          // 162408 stored rows in symmetric mode
#define KSEL 100
#define BN_EPS 1e-5f
#define SLOPE 0.01f

__device__ __forceinline__ float lrelu(float v) { return v >= 0.f ? v : SLOPE * v; }

// ---- triangle index helpers (upper triangle incl. diagonal, row-major) ----
__device__ __forceinline__ int tri_base(int i) { return i * NV - (i * (i - 1)) / 2; }
__device__ __forceinline__ void tri_decode(int s, int& b, int& i, int& j) {
    b = s / TRI;
    int t = s - b * TRI;
    float disc = (float)(403 * 403) - 8.0f * (float)t;   // (2*NV+1)^2 - 8t
    int ii = (int)((403.0f - sqrtf(disc)) * 0.5f);
    if (ii < 0) ii = 0;
    if (ii > NV - 1) ii = NV - 1;
    while (ii < NV - 1 && tri_base(ii + 1) <= t) ++ii;
    while (ii > 0 && tri_base(ii) > t) --ii;
    i = ii;
    j = t - tri_base(ii) + ii;
}

__device__ __forceinline__ float4 ld4(const float* p) { return *(const float4*)p; }

__global__ void zero_stats(double* p) { p[blockIdx.x * 256 + threadIdx.x] = 0.0; }

// Fused: [pairwise |xi-xj| gen (MODE 0) | BN+LeakyReLU on load (MODE 1)] -> 1x1 conv
// -> store (stride 256) + per-channel weighted sum/sumsq (double atomics) for next BN.
// Rows are upper-triangle pixels; off-diagonal rows carry stats weight 2.
// SINGLE-OWNER tiles -> safe in-place. Register tile 8x16 / 16x8 per thread:
// per k-step 128 FMA vs 6 ds_read_b128 (LDS/VALU ~28%, was ~94% with 4x16).
template<int CIN, int COUT, int MODE, int BM>
__global__ __launch_bounds__(256, 3)
void gemm_bn(const float* xin,               // MODE 0 source ([8,201,256] fp32)
             const float* in,                // MODE 1 source (element stride 256)
             const float* __restrict__ W,    // [COUT, CIN]
             const float* __restrict__ scale,
             const float* __restrict__ shift,
             float* out,                     // element stride 256 (may alias `in`)
             double* __restrict__ stat_sum,
             double* __restrict__ stat_sq)
{
    constexpr int BK  = 32;
    constexpr int RPT = BM / 16;     // rows per thread (8 or 16)
    constexpr int CPT = COUT / 16;   // cols per thread (16 or 8)
    __shared__ float As[BK][BM + 4];
    __shared__ float Bs[BK][COUT + 4];
    __shared__ float csum[COUT];
    __shared__ float csq[COUT];
    __shared__ float wg[BM];                      // stats weight per row (1 diag / 2 off)
    __shared__ int   rbi[(MODE == 0) ? BM : 1];   // b*NV+i (MODE 0)
    __shared__ int   rbj[(MODE == 0) ? BM : 1];   // b*NV+j (MODE 0)

    const int t  = threadIdx.x;
    const int tx = t & 15;
    const int ty = t >> 4;
    const int m0 = blockIdx.x * BM;

    // once-per-block row decode (was per k-tile: ~8x redundant VALU)
    for (int m = t; m < BM; m += 256) {
        int pix = m0 + m;
        int b, i, j;
        if (pix < NSYM) {
            tri_decode(pix, b, i, j);
            wg[m] = (i == j) ? 1.f : 2.f;
            if constexpr (MODE == 0) { rbi[m] = b * NV + i; rbj[m] = b * NV + j; }
        } else {
            wg[m] = 0.f;
            if constexpr (MODE == 0) { rbi[m] = 0; rbj[m] = 0; }
        }
    }
    __syncthreads();

    float acc[RPT][CPT];
    #pragma unroll
    for (int i = 0; i < RPT; ++i)
        #pragma unroll
        for (int j = 0; j < CPT; ++j) acc[i][j] = 0.f;

    for (int kt = 0; kt < CIN; kt += BK) {
        // ---- stage A tile (transposed into LDS) ----
        #pragma unroll
        for (int f = 0; f < BM / 32; ++f) {
            int flat = t + 256 * f;          // BM rows x 8 float4
            int m    = flat >> 3;
            int kq   = flat & 7;
            int k    = kt + kq * 4;
            int pix  = m0 + m;
            float4 v = make_float4(0.f, 0.f, 0.f, 0.f);
            if (pix < NSYM) {
                if constexpr (MODE == 0) {
                    float4 xi = *(const float4*)(xin + (size_t)rbi[m] * ND + k);
                    float4 xj = *(const float4*)(xin + (size_t)rbj[m] * ND + k);
                    v = make_float4(fabsf(xi.x - xj.x), fabsf(xi.y - xj.y),
                                    fabsf(xi.z - xj.z), fabsf(xi.w - xj.w));
                } else {
                    float4 u  = ld4(in + (size_t)pix * 256 + k);
                    float4 sc = *(const float4*)(scale + k);
                    float4 sh = *(const float4*)(shift + k);
                    v.x = lrelu(fmaf(u.x, sc.x, sh.x));
                    v.y = lrelu(fmaf(u.y, sc.y, sh.y));
                    v.z = lrelu(fmaf(u.z, sc.z, sh.z));
                    v.w = lrelu(fmaf(u.w, sc.w, sh.w));
                }
            }
            As[kq * 4 + 0][m] = v.x;
            As[kq * 4 + 1][m] = v.y;
            As[kq * 4 + 2][m] = v.z;
            As[kq * 4 + 3][m] = v.w;
        }
        // ---- stage B tile (W transposed into LDS) ----
        #pragma unroll
        for (int f = 0; f < COUT / 32; ++f) {
            int flat = t + 256 * f;          // COUT rows x 8 float4
            int n    = flat >> 3;
            int kq   = flat & 7;
            int k    = kt + kq * 4;
            float4 w = *(const float4*)(W + (size_t)n * CIN + k);
            Bs[kq * 4 + 0][n] = w.x;
            Bs[kq * 4 + 1][n] = w.y;
            Bs[kq * 4 + 2][n] = w.z;
            Bs[kq * 4 + 3][n] = w.w;
        }
        __syncthreads();
        // ---- inner product: RPT x CPT register tile ----
        #pragma unroll 4
        for (int k = 0; k < BK; ++k) {
            float a[RPT], b[CPT];
            #pragma unroll
            for (int rc = 0; rc < RPT / 4; ++rc)
                *(float4*)&a[rc * 4] = *(const float4*)&As[k][rc * 64 + ty * 4];
            #pragma unroll
            for (int cc = 0; cc < CPT / 4; ++cc)
                *(float4*)&b[cc * 4] = *(const float4*)&Bs[k][cc * 64 + tx * 4];
            #pragma unroll
            for (int i = 0; i < RPT; ++i)
                #pragma unroll
                for (int j = 0; j < CPT; ++j)
                    acc[i][j] = fmaf(a[i], b[j], acc[i][j]);
        }
        __syncthreads();
    }

    // ---- epilogue: stores + weighted per-channel stats (unrounded fp32 acc) ----
    for (int n = t; n < COUT; n += 256) { csum[n] = 0.f; csq[n] = 0.f; }
    __syncthreads();

    float tsum[CPT], tsq[CPT];
    #pragma unroll
    for (int j = 0; j < CPT; ++j) { tsum[j] = 0.f; tsq[j] = 0.f; }

    #pragma unroll
    for (int i = 0; i < RPT; ++i) {
        int m   = (i >> 2) * 64 + ty * 4 + (i & 3);
        int pix = m0 + m;
        if (pix < NSYM) {
            float w = wg[m];
            #pragma unroll
            for (int j = 0; j < CPT; ++j) {
                float v = acc[i][j];
                tsum[j] += w * v;
                tsq[j]  += w * v * v;
            }
            #pragma unroll
            for (int cc = 0; cc < CPT / 4; ++cc) {
                float4 v = make_float4(acc[i][cc * 4 + 0], acc[i][cc * 4 + 1],
                                       acc[i][cc * 4 + 2], acc[i][cc * 4 + 3]);
                *(float4*)(out + (size_t)pix * 256 + cc * 64 + tx * 4) = v;
            }
        }
    }
    #pragma unroll
    for (int j = 0; j < CPT; ++j) {
        int n = (j >> 2) * 64 + tx * 4 + (j & 3);
        atomicAdd(&csum[n], tsum[j]);
        atomicAdd(&csq[n],  tsq[j]);
    }
    __syncthreads();
    for (int n = t; n < COUT; n += 256) {
        atomicAdd(&stat_sum[n], (double)csum[n]);
        atomicAdd(&stat_sq[n],  (double)csq[n]);
    }
}

// double stats -> BN scale/shift (conv bias cancels exactly inside BatchNorm -> skipped)
__global__ void bn_finalize(const double* __restrict__ ssum, const double* __restrict__ ssq,
                            const float* __restrict__ g, const float* __restrict__ be,
                            float* __restrict__ scale, float* __restrict__ shift, int C)
{
    int c = threadIdx.x + blockIdx.x * blockDim.x;
    if (c < C) {
        double m = ssum[c] * (1.0 / NPIX);
        double v = ssq[c] * (1.0 / NPIX) - m * m;   // jnp.var, ddof=0
        float s = g[c] / sqrtf((float)v + BN_EPS);
        scale[c] = s;
        shift[c] = be[c] - (float)m * s;
    }
}

// BN3 + LeakyReLU + dot(w4) + b4 for every triangle row -> logit_tri[NSYM]
__global__ __launch_bounds__(256)
void logits_tri(const float* __restrict__ act,   // [NSYM, 256] (first 128 ch valid)
                const float* __restrict__ scale, const float* __restrict__ shift,
                const float* __restrict__ w4, const float* __restrict__ b4,
                float* __restrict__ lt)
{
    int s = blockIdx.x * 256 + threadIdx.x;
    if (s >= NSYM) return;
    const float* p = act + (size_t)s * 256;
    float acc = 0.f;
    #pragma unroll
    for (int c = 0; c < 128; c += 4) {
        float4 u  = ld4(p + c);
        float4 sc = *(const float4*)(scale + c);
        float4 sh = *(const float4*)(shift + c);
        float4 w  = *(const float4*)(w4 + c);
        acc += lrelu(fmaf(u.x, sc.x, sh.x)) * w.x;
        acc += lrelu(fmaf(u.y, sc.y, sh.y)) * w.y;
        acc += lrelu(fmaf(u.z, sc.z, sh.z)) * w.z;
        acc += lrelu(fmaf(u.w, sc.w, sh.w)) * w.w;
    }
    lt[s] = acc + b4[0];
}

// gather symmetric logits -> softmax over j -> top-K rank mask (stable tie-break)
__global__ __launch_bounds__(256)
void final_softmax_topk_sym(const float* __restrict__ lt, float* __restrict__ outp)
{
    __shared__ float sv[NV];
    __shared__ float red[256];
    const int row = blockIdx.x;                 // b*NV + i
    const int b   = row / NV;
    const int i   = row - b * NV;
    const int t   = threadIdx.x;

    float logit = -INFINITY;
    if (t < NV) {
        int jm = (i < t) ? i : t;
        int jM = (i < t) ? t : i;
        logit = lt[b * TRI + tri_base(jm) + (jM - jm)];
    }
    red[t] = logit;
    __syncthreads();
    #pragma unroll
    for (int off = 128; off > 0; off >>= 1) {
        if (t < off) red[t] = fmaxf(red[t], red[t + off]);
        __syncthreads();
    }
    float mx = red[0];
    __syncthreads();
    float e = (t < NV) ? expf(logit - mx) : 0.f;
    red[t] = e;
    __syncthreads();
    #pragma unroll
    for (int off = 128; off > 0; off >>= 1) {
        if (t < off) red[t] += red[t + off];
        __syncthreads();
    }
    float denom = red[0];
    __syncthreads();
    float val = e / denom;
    if (t < NV) sv[t] = val;
    __syncthreads();
    if (t < NV) {
        int rank = 0;
        for (int j = 0; j < NV; ++j) {
            float o = sv[j];
            rank += (o > val || (o == val && j < t)) ? 1 : 0;
        }
        outp[(size_t)row * NV + t] = (rank < KSEL) ? val : 0.f;
    }
}

extern "C" void kernel_launch(void* const* d_in, const int* in_sizes, int n_in,
                              void* d_out, int out_size, void* d_ws, size_t ws_size,
                              hipStream_t stream)
{
    (void)in_sizes; (void)n_in; (void)out_size; (void)ws_size;

    const float* x   = (const float*)d_in[0];
    const float* w0  = (const float*)d_in[1];
    const float* g0  = (const float*)d_in[3];
    const float* be0 = (const float*)d_in[4];
    const float* w1  = (const float*)d_in[5];
    const float* g1  = (const float*)d_in[7];
    const float* be1 = (const float*)d_in[8];
    const float* w2  = (const float*)d_in[9];
    const float* g2  = (const float*)d_in[11];
    const float* be2 = (const float*)d_in[12];
    const float* w3  = (const float*)d_in[13];
    const float* g3  = (const float*)d_in[15];
    const float* be3 = (const float*)d_in[16];
    const float* w4  = (const float*)d_in[17];
    const float* b4  = (const float*)d_in[18];
    // b0..b3 unused: conv bias cancels exactly in the following BatchNorm.

    char* ws = (char*)d_ws;
    // layout: [double stats 16KB][scale/shift 8KB][logit_tri 650KB][activation buffer]
    double* D    = (double*)ws;                    // 4 stages x (sum[256]|sq[256])
    float*  F    = (float*)(ws + 16384);           // 4 stages x (scale[256]|shift[256])
    float*  lt   = (float*)(ws + 16384 + 8192);
    float*  buf  = (float*)(ws + 16384 + 8192 + 655360);
    float*  outp = (float*)d_out;

    zero_stats<<<8, 256, 0, stream>>>(D);

    const int g128 = (NSYM + 127) / 128;   // 1269
    const int g256 = (NSYM + 255) / 256;   // 635

    // L0: |xi-xj| -> conv0 (256->256), 128x256 tile
    gemm_bn<256, 256, 0, 128><<<g128, 256, 0, stream>>>(
        x, nullptr, w0, nullptr, nullptr, buf, D + 0, D + 256);
    bn_finalize<<<1, 256, 0, stream>>>(D + 0, D + 256, g0, be0, F + 0, F + 256, 256);

    // L1: BN0+LReLU -> conv1 (256->256), in-place, 128x256 tile
    gemm_bn<256, 256, 1, 128><<<g128, 256, 0, stream>>>(
        nullptr, buf, w1, F + 0, F + 256, buf, D + 512, D + 768);
    bn_finalize<<<1, 256, 0, stream>>>(D + 512, D + 768, g1, be1, F + 512, F + 768, 256);

    // L2: BN1+LReLU -> conv2 (256->128), in-place, 256x128 tile
    gemm_bn<256, 128, 1, 256><<<g256, 256, 0, stream>>>(
        nullptr, buf, w2, F + 512, F + 768, buf, D + 1024, D + 1280);
    bn_finalize<<<1, 256, 0, stream>>>(D + 1024, D + 1280, g2, be2, F + 1024, F + 1280, 128);

    // L3: BN2+LReLU -> conv3 (128->128), in-place, 256x128 tile
    gemm_bn<128, 128, 1, 256><<<g256, 256, 0, stream>>>(
        nullptr, buf, w3, F + 1024, F + 1280, buf, D + 1536, D + 1792);
    bn_finalize<<<1, 256, 0, stream>>>(D + 1536, D + 1792, g3, be3, F + 1536, F + 1792, 128);

    logits_tri<<<(NSYM + 255) / 256, 256, 0, stream>>>(buf, F + 1536, F + 1792, w4, b4, lt);
    final_softmax_topk_sym<<<NB * NV, 256, 0, stream>>>(lt, outp);
}

// Round 8
// 1046.931 us; speedup vs baseline: 5.9161x; 5.9161x over previous
//
#include <hip/hip_runtime.h>
#include <math.h>

#define NB 8
#define NV 201
#define ND 256
#define NPIX (NB*NV*NV)        // 323208 (full pixel count; BN normalizer)
#define TRI  (NV*(NV+1)/2)     // 20301 upper-triangle pixels per batch (i<=j)
#define NSYM (NB*TRI)          // 162408 stored rows in symmetric mode
#define KSEL 100
#define BN_EPS 1e-5f
#define SLOPE 0.01f

__device__ __forceinline__ float lrelu(float v) { return v >= 0.f ? v : SLOPE * v; }

// ---- triangle index helpers (upper triangle incl. diagonal, row-major) ----
__device__ __forceinline__ int tri_base(int i) { return i * NV - (i * (i - 1)) / 2; }
__device__ __forceinline__ void tri_decode(int s, int& b, int& i, int& j) {
    b = s / TRI;
    int t = s - b * TRI;
    float disc = (float)(403 * 403) - 8.0f * (float)t;   // (2*NV+1)^2 - 8t
    int ii = (int)((403.0f - sqrtf(disc)) * 0.5f);
    if (ii < 0) ii = 0;
    if (ii > NV - 1) ii = NV - 1;
    while (ii < NV - 1 && tri_base(ii + 1) <= t) ++ii;
    while (ii > 0 && tri_base(ii) > t) --ii;
    i = ii;
    j = t - tri_base(ii) + ii;
}

__device__ __forceinline__ float4 ld4(const float* p) { return *(const float4*)p; }

__global__ void zero_stats(double* p) { p[blockIdx.x * 256 + threadIdx.x] = 0.0; }

// Fused: [pairwise |xi-xj| gen (MODE 0) | BN+LeakyReLU on load (MODE 1)] -> 1x1 conv
// -> store (stride 256) + per-channel weighted sum/sumsq (double atomics) for next BN.
// Rows are upper-triangle pixels; off-diagonal rows carry stats weight 2.
// SINGLE-OWNER tiles -> safe in-place. Register tile 8x16 / 16x8 per thread.
// NOTE: no min-waves arg in launch_bounds! (256,3) capped VGPR at 84 -> the 128
// accumulators spilled to scratch: 6.5 GB WRITE_SIZE/dispatch, VALUBusy 6%, 5.4x slower.
template<int CIN, int COUT, int MODE, int BM>
__global__ __launch_bounds__(256)
void gemm_bn(const float* xin,               // MODE 0 source ([8,201,256] fp32)
             const float* in,                // MODE 1 source (element stride 256)
             const float* __restrict__ W,    // [COUT, CIN]
             const float* __restrict__ scale,
             const float* __restrict__ shift,
             float* out,                     // element stride 256 (may alias `in`)
             double* __restrict__ stat_sum,
             double* __restrict__ stat_sq)
{
    constexpr int BK  = 32;
    constexpr int RPT = BM / 16;     // rows per thread (8 or 16)
    constexpr int CPT = COUT / 16;   // cols per thread (16 or 8)
    __shared__ float As[BK][BM + 4];
    __shared__ float Bs[BK][COUT + 4];
    __shared__ float csum[COUT];
    __shared__ float csq[COUT];
    __shared__ float wg[BM];                      // stats weight per row (1 diag / 2 off)
    __shared__ int   rbi[(MODE == 0) ? BM : 1];   // b*NV+i (MODE 0)
    __shared__ int   rbj[(MODE == 0) ? BM : 1];   // b*NV+j (MODE 0)

    const int t  = threadIdx.x;
    const int tx = t & 15;
    const int ty = t >> 4;
    const int m0 = blockIdx.x * BM;

    // once-per-block row decode (was per k-tile: ~8x redundant VALU)
    for (int m = t; m < BM; m += 256) {
        int pix = m0 + m;
        int b, i, j;
        if (pix < NSYM) {
            tri_decode(pix, b, i, j);
            wg[m] = (i == j) ? 1.f : 2.f;
            if constexpr (MODE == 0) { rbi[m] = b * NV + i; rbj[m] = b * NV + j; }
        } else {
            wg[m] = 0.f;
            if constexpr (MODE == 0) { rbi[m] = 0; rbj[m] = 0; }
        }
    }
    __syncthreads();

    float acc[RPT][CPT];
    #pragma unroll
    for (int i = 0; i < RPT; ++i)
        #pragma unroll
        for (int j = 0; j < CPT; ++j) acc[i][j] = 0.f;

    for (int kt = 0; kt < CIN; kt += BK) {
        // ---- stage A tile (transposed into LDS) ----
        #pragma unroll
        for (int f = 0; f < BM / 32; ++f) {
            int flat = t + 256 * f;          // BM rows x 8 float4
            int m    = flat >> 3;
            int kq   = flat & 7;
            int k    = kt + kq * 4;
            int pix  = m0 + m;
            float4 v = make_float4(0.f, 0.f, 0.f, 0.f);
            if (pix < NSYM) {
                if constexpr (MODE == 0) {
                    float4 xi = *(const float4*)(xin + (size_t)rbi[m] * ND + k);
                    float4 xj = *(const float4*)(xin + (size_t)rbj[m] * ND + k);
                    v = make_float4(fabsf(xi.x - xj.x), fabsf(xi.y - xj.y),
                                    fabsf(xi.z - xj.z), fabsf(xi.w - xj.w));
                } else {
                    float4 u  = ld4(in + (size_t)pix * 256 + k);
                    float4 sc = *(const float4*)(scale + k);
                    float4 sh = *(const float4*)(shift + k);
                    v.x = lrelu(fmaf(u.x, sc.x, sh.x));
                    v.y = lrelu(fmaf(u.y, sc.y, sh.y));
                    v.z = lrelu(fmaf(u.z, sc.z, sh.z));
                    v.w = lrelu(fmaf(u.w, sc.w, sh.w));
                }
            }
            As[kq * 4 + 0][m] = v.x;
            As[kq * 4 + 1][m] = v.y;
            As[kq * 4 + 2][m] = v.z;
            As[kq * 4 + 3][m] = v.w;
        }
        // ---- stage B tile (W transposed into LDS) ----
        #pragma unroll
        for (int f = 0; f < COUT / 32; ++f) {
            int flat = t + 256 * f;          // COUT rows x 8 float4
            int n    = flat >> 3;
            int kq   = flat & 7;
            int k    = kt + kq * 4;
            float4 w = *(const float4*)(W + (size_t)n * CIN + k);
            Bs[kq * 4 + 0][n] = w.x;
            Bs[kq * 4 + 1][n] = w.y;
            Bs[kq * 4 + 2][n] = w.z;
            Bs[kq * 4 + 3][n] = w.w;
        }
        __syncthreads();
        // ---- inner product: RPT x CPT register tile ----
        #pragma unroll 4
        for (int k = 0; k < BK; ++k) {
            float a[RPT], b[CPT];
            #pragma unroll
            for (int rc = 0; rc < RPT / 4; ++rc)
                *(float4*)&a[rc * 4] = *(const float4*)&As[k][rc * 64 + ty * 4];
            #pragma unroll
            for (int cc = 0; cc < CPT / 4; ++cc)
                *(float4*)&b[cc * 4] = *(const float4*)&Bs[k][cc * 64 + tx * 4];
            #pragma unroll
            for (int i = 0; i < RPT; ++i)
                #pragma unroll
                for (int j = 0; j < CPT; ++j)
                    acc[i][j] = fmaf(a[i], b[j], acc[i][j]);
        }
        __syncthreads();
    }

    // ---- epilogue: stores + weighted per-channel stats (unrounded fp32 acc) ----
    for (int n = t; n < COUT; n += 256) { csum[n] = 0.f; csq[n] = 0.f; }
    __syncthreads();

    float tsum[CPT], tsq[CPT];
    #pragma unroll
    for (int j = 0; j < CPT; ++j) { tsum[j] = 0.f; tsq[j] = 0.f; }

    #pragma unroll
    for (int i = 0; i < RPT; ++i) {
        int m   = (i >> 2) * 64 + ty * 4 + (i & 3);
        int pix = m0 + m;
        if (pix < NSYM) {
            float w = wg[m];
            #pragma unroll
            for (int j = 0; j < CPT; ++j) {
                float v = acc[i][j];
                tsum[j] += w * v;
                tsq[j]  += w * v * v;
            }
            #pragma unroll
            for (int cc = 0; cc < CPT / 4; ++cc) {
                float4 v = make_float4(acc[i][cc * 4 + 0], acc[i][cc * 4 + 1],
                                       acc[i][cc * 4 + 2], acc[i][cc * 4 + 3]);
                *(float4*)(out + (size_t)pix * 256 + cc * 64 + tx * 4) = v;
            }
        }
    }
    #pragma unroll
    for (int j = 0; j < CPT; ++j) {
        int n = (j >> 2) * 64 + tx * 4 + (j & 3);
        atomicAdd(&csum[n], tsum[j]);
        atomicAdd(&csq[n],  tsq[j]);
    }
    __syncthreads();
    for (int n = t; n < COUT; n += 256) {
        atomicAdd(&stat_sum[n], (double)csum[n]);
        atomicAdd(&stat_sq[n],  (double)csq[n]);
    }
}

// double stats -> BN scale/shift (conv bias cancels exactly inside BatchNorm -> skipped)
__global__ void bn_finalize(const double* __restrict__ ssum, const double* __restrict__ ssq,
                            const float* __restrict__ g, const float* __restrict__ be,
                            float* __restrict__ scale, float* __restrict__ shift, int C)
{
    int c = threadIdx.x + blockIdx.x * blockDim.x;
    if (c < C) {
        double m = ssum[c] * (1.0 / NPIX);
        double v = ssq[c] * (1.0 / NPIX) - m * m;   // jnp.var, ddof=0
        float s = g[c] / sqrtf((float)v + BN_EPS);
        scale[c] = s;
        shift[c] = be[c] - (float)m * s;
    }
}

// BN3 + LeakyReLU + dot(w4) + b4 for every triangle row -> logit_tri[NSYM]
__global__ __launch_bounds__(256)
void logits_tri(const float* __restrict__ act,   // [NSYM, 256] (first 128 ch valid)
                const float* __restrict__ scale, const float* __restrict__ shift,
                const float* __restrict__ w4, const float* __restrict__ b4,
                float* __restrict__ lt)
{
    int s = blockIdx.x * 256 + threadIdx.x;
    if (s >= NSYM) return;
    const float* p = act + (size_t)s * 256;
    float acc = 0.f;
    #pragma unroll
    for (int c = 0; c < 128; c += 4) {
        float4 u  = ld4(p + c);
        float4 sc = *(const float4*)(scale + c);
        float4 sh = *(const float4*)(shift + c);
        float4 w  = *(const float4*)(w4 + c);
        acc += lrelu(fmaf(u.x, sc.x, sh.x)) * w.x;
        acc += lrelu(fmaf(u.y, sc.y, sh.y)) * w.y;
        acc += lrelu(fmaf(u.z, sc.z, sh.z)) * w.z;
        acc += lrelu(fmaf(u.w, sc.w, sh.w)) * w.w;
    }
    lt[s] = acc + b4[0];
}

// gather symmetric logits -> softmax over j -> top-K rank mask (stable tie-break)
__global__ __launch_bounds__(256)
void final_softmax_topk_sym(const float* __restrict__ lt, float* __restrict__ outp)
{
    __shared__ float sv[NV];
    __shared__ float red[256];
    const int row = blockIdx.x;                 // b*NV + i
    const int b   = row / NV;
    const int i   = row - b * NV;
    const int t   = threadIdx.x;

    float logit = -INFINITY;
    if (t < NV) {
        int jm = (i < t) ? i : t;
        int jM = (i < t) ? t : i;
        logit = lt[b * TRI + tri_base(jm) + (jM - jm)];
    }
    red[t] = logit;
    __syncthreads();
    #pragma unroll
    for (int off = 128; off > 0; off >>= 1) {
        if (t < off) red[t] = fmaxf(red[t], red[t + off]);
        __syncthreads();
    }
    float mx = red[0];
    __syncthreads();
    float e = (t < NV) ? expf(logit - mx) : 0.f;
    red[t] = e;
    __syncthreads();
    #pragma unroll
    for (int off = 128; off > 0; off >>= 1) {
        if (t < off) red[t] += red[t + off];
        __syncthreads();
    }
    float denom = red[0];
    __syncthreads();
    float val = e / denom;
    if (t < NV) sv[t] = val;
    __syncthreads();
    if (t < NV) {
        int rank = 0;
        for (int j = 0; j < NV; ++j) {
            float o = sv[j];
            rank += (o > val || (o == val && j < t)) ? 1 : 0;
        }
        outp[(size_t)row * NV + t] = (rank < KSEL) ? val : 0.f;
    }
}

extern "C" void kernel_launch(void* const* d_in, const int* in_sizes, int n_in,
                              void* d_out, int out_size, void* d_ws, size_t ws_size,
                              hipStream_t stream)
{
    (void)in_sizes; (void)n_in; (void)out_size; (void)ws_size;

    const float* x   = (const float*)d_in[0];
    const float* w0  = (const float*)d_in[1];
    const float* g0  = (const float*)d_in[3];
    const float* be0 = (const float*)d_in[4];
    const float* w1  = (const float*)d_in[5];
    const float* g1  = (const float*)d_in[7];
    const float* be1 = (const float*)d_in[8];
    const float* w2  = (const float*)d_in[9];
    const float* g2  = (const float*)d_in[11];
    const float* be2 = (const float*)d_in[12];
    const float* w3  = (const float*)d_in[13];
    const float* g3  = (const float*)d_in[15];
    const float* be3 = (const float*)d_in[16];
    const float* w4  = (const float*)d_in[17];
    const float* b4  = (const float*)d_in[18];
    // b0..b3 unused: conv bias cancels exactly in the following BatchNorm.

    char* ws = (char*)d_ws;
    // layout: [double stats 16KB][scale/shift 8KB][logit_tri 650KB][activation buffer]
    double* D    = (double*)ws;                    // 4 stages x (sum[256]|sq[256])
    float*  F    = (float*)(ws + 16384);           // 4 stages x (scale[256]|shift[256])
    float*  lt   = (float*)(ws + 16384 + 8192);
    float*  buf  = (float*)(ws + 16384 + 8192 + 655360);
    float*  outp = (float*)d_out;

    zero_stats<<<8, 256, 0, stream>>>(D);

    const int g128 = (NSYM + 127) / 128;   // 1269
    const int g256 = (NSYM + 255) / 256;   // 635

    // L0: |xi-xj| -> conv0 (256->256), 128x256 tile
    gemm_bn<256, 256, 0, 128><<<g128, 256, 0, stream>>>(
        x, nullptr, w0, nullptr, nullptr, buf, D + 0, D + 256);
    bn_finalize<<<1, 256, 0, stream>>>(D + 0, D + 256, g0, be0, F + 0, F + 256, 256);

    // L1: BN0+LReLU -> conv1 (256->256), in-place, 128x256 tile
    gemm_bn<256, 256, 1, 128><<<g128, 256, 0, stream>>>(
        nullptr, buf, w1, F + 0, F + 256, buf, D + 512, D + 768);
    bn_finalize<<<1, 256, 0, stream>>>(D + 512, D + 768, g1, be1, F + 512, F + 768, 256);

    // L2: BN1+LReLU -> conv2 (256->128), in-place, 256x128 tile
    gemm_bn<256, 128, 1, 256><<<g256, 256, 0, stream>>>(
        nullptr, buf, w2, F + 512, F + 768, buf, D + 1024, D + 1280);
    bn_finalize<<<1, 256, 0, stream>>>(D + 1024, D + 1280, g2, be2, F + 1024, F + 1280, 128);

    // L3: BN2+LReLU -> conv3 (128->128), in-place, 256x128 tile
    gemm_bn<128, 128, 1, 256><<<g256, 256, 0, stream>>>(
        nullptr, buf, w3, F + 1024, F + 1280, buf, D + 1536, D + 1792);
    bn_finalize<<<1, 256, 0, stream>>>(D + 1536, D + 1792, g3, be3, F + 1536, F + 1792, 128);

    logits_tri<<<(NSYM + 255) / 256, 256, 0, stream>>>(buf, F + 1536, F + 1792, w4, b4, lt);
    final_softmax_topk_sym<<<NB * NV, 256, 0, stream>>>(lt, outp);
}

// Round 13
// 685.295 us; speedup vs baseline: 9.0381x; 1.5277x over previous
//
#include <hip/hip_runtime.h>
#include <math.h>

#define NB 8
#define NV 201
#define ND 256
#define NPIX (NB*NV*NV)        // 323208 (full pixel count; BN normalizer)
#define TRI  (NV*(NV+1)/2)     // 20301 upper-triangle pixels per batch (i<=j)
#define NSYM (NB*TRI)          // 162408 stored rows in symmetric mode
#define KSEL 100
#define BN_EPS 1e-5f
#define SLOPE 0.01f

__device__ __forceinline__ float lrelu(float v) { return v >= 0.f ? v : SLOPE * v; }

typedef _Float16 half4_t __attribute__((ext_vector_type(4)));
typedef _Float16 half8   __attribute__((ext_vector_type(8)));
typedef float    f32x4   __attribute__((ext_vector_type(4)));

// fp16x2 split, by-value (vector elements cannot bind to C++ references — r11 lesson):
// hi = (f16)x ; lo = (f16)(x - (float)hi). x - hi is exact in fp32.
__device__ __forceinline__ half4_t to_h4(float4 v) {
    half4_t h;
    h.x = (_Float16)v.x; h.y = (_Float16)v.y;
    h.z = (_Float16)v.z; h.w = (_Float16)v.w;
    return h;
}
__device__ __forceinline__ half4_t residual_h4(float4 v, half4_t h) {
    half4_t l;
    l.x = (_Float16)(v.x - (float)h.x); l.y = (_Float16)(v.y - (float)h.y);
    l.z = (_Float16)(v.z - (float)h.z); l.w = (_Float16)(v.w - (float)h.w);
    return l;
}

// ---- triangle index helpers (upper triangle incl. diagonal, row-major) ----
__device__ __forceinline__ int tri_base(int i) { return i * NV - (i * (i - 1)) / 2; }
__device__ __forceinline__ void tri_decode(int s, int& b, int& i, int& j) {
    b = s / TRI;
    int t = s - b * TRI;
    float disc = (float)(403 * 403) - 8.0f * (float)t;   // (2*NV+1)^2 - 8t
    int ii = (int)((403.0f - sqrtf(disc)) * 0.5f);
    if (ii < 0) ii = 0;
    if (ii > NV - 1) ii = NV - 1;
    while (ii < NV - 1 && tri_base(ii + 1) <= t) ++ii;
    while (ii > 0 && tri_base(ii) > t) --ii;
    i = ii;
    j = t - tri_base(ii) + ii;
}

__device__ __forceinline__ float4 ld4(const float* p) { return *(const float4*)p; }

__global__ void zero_stats(double* p) { p[blockIdx.x * 256 + threadIdx.x] = 0.0; }

// MFMA GEMM with fp16x2-split (fp32-faithful): C = Ah*Bh + Ah*Bl + Al*Bh, fp32 acc.
// [pairwise |xi-xj| gen (MODE 0) | BN+LeakyReLU on load (MODE 1)] -> conv -> store
// (stride 256) + weighted per-channel sum/sumsq (double atomics) for next BN.
// Fragment layout (verified facts): C/D col=lane&15, row=(lane>>4)*4+reg [m89/m91];
// A/B: lane&15 = row(A)/col(B), lane>>4 = k-group (m162 tr-read pattern); intra-frag
// k-order is permutation-invariant since A and B use the same [idx][k] formula.
// W is [COUT][CIN] row-major == B^T form, matching the D-row<-first-operand convention.
// SINGLE-OWNER tiles -> safe in-place. NO min-waves in launch_bounds (round-7 lesson).
template<int CIN, int COUT, int MODE>
__global__ __launch_bounds__(256)
void gemm_bn_mfma(const float* xin,               // MODE 0 source ([8,201,256] fp32)
                  const float* in,                // MODE 1 source (element stride 256)
                  const float* __restrict__ W,    // [COUT, CIN]
                  const float* __restrict__ scale,
                  const float* __restrict__ shift,
                  float* out,                     // element stride 256 (may alias `in`)
                  double* __restrict__ stat_sum,
                  double* __restrict__ stat_sq)
{
    constexpr int BM  = 128;
    constexpr int BK  = 32;
    constexpr int PAD = 40;          // 80B row stride: 16B-aligned b128 reads, <=2-way banks
    constexpr int NCT = COUT / 16;   // 16 or 8 col-tiles
    __shared__ __align__(16) _Float16 Ah[BM][PAD];
    __shared__ __align__(16) _Float16 Al[BM][PAD];
    __shared__ __align__(16) _Float16 Bh[COUT][PAD];
    __shared__ __align__(16) _Float16 Bl[COUT][PAD];
    __shared__ float wg[BM];                      // stats weight (1 diag / 2 off-diag)
    __shared__ int   rbi[(MODE == 0) ? BM : 1];
    __shared__ int   rbj[(MODE == 0) ? BM : 1];

    const int t    = threadIdx.x;
    const int lane = t & 63;
    const int wv   = t >> 6;         // wave 0..3 owns rows [wv*32, wv*32+32)
    const int l15  = lane & 15;
    const int lk   = lane >> 4;      // k-group / C-row-group
    const int m0   = blockIdx.x * BM;

    for (int m = t; m < BM; m += 256) {
        int pix = m0 + m;
        int b, i, j;
        if (pix < NSYM) {
            tri_decode(pix, b, i, j);
            wg[m] = (i == j) ? 1.f : 2.f;
            if constexpr (MODE == 0) { rbi[m] = b * NV + i; rbj[m] = b * NV + j; }
        } else {
            wg[m] = 0.f;
            if constexpr (MODE == 0) { rbi[m] = 0; rbj[m] = 0; }
        }
    }
    __syncthreads();

    f32x4 acc[2][NCT];
    #pragma unroll
    for (int rt = 0; rt < 2; ++rt)
        #pragma unroll
        for (int nc = 0; nc < NCT; ++nc) {
            acc[rt][nc][0] = 0.f; acc[rt][nc][1] = 0.f;
            acc[rt][nc][2] = 0.f; acc[rt][nc][3] = 0.f;
        }

    for (int kt = 0; kt < CIN; kt += BK) {
        // ---- stage A tile: [m][k] halves, hi/lo split ----
        #pragma unroll
        for (int f = 0; f < BM / 32; ++f) {
            int flat = t + 256 * f;          // BM rows x 8 float4
            int m    = flat >> 3;
            int kq   = flat & 7;
            int k    = kt + kq * 4;
            int pix  = m0 + m;
            float4 v = make_float4(0.f, 0.f, 0.f, 0.f);
            if (pix < NSYM) {
                if constexpr (MODE == 0) {
                    float4 xi = *(const float4*)(xin + (size_t)rbi[m] * ND + k);
                    float4 xj = *(const float4*)(xin + (size_t)rbj[m] * ND + k);
                    v = make_float4(fabsf(xi.x - xj.x), fabsf(xi.y - xj.y),
                                    fabsf(xi.z - xj.z), fabsf(xi.w - xj.w));
                } else {
                    float4 u  = ld4(in + (size_t)pix * 256 + k);
                    float4 sc = *(const float4*)(scale + k);
                    float4 sh = *(const float4*)(shift + k);
                    v.x = lrelu(fmaf(u.x, sc.x, sh.x));
                    v.y = lrelu(fmaf(u.y, sc.y, sh.y));
                    v.z = lrelu(fmaf(u.z, sc.z, sh.z));
                    v.w = lrelu(fmaf(u.w, sc.w, sh.w));
                }
            }
            half4_t vh = to_h4(v);
            half4_t vl = residual_h4(v, vh);
            *(half4_t*)&Ah[m][kq * 4] = vh;
            *(half4_t*)&Al[m][kq * 4] = vl;
        }
        // ---- stage B tile (W rows), hi/lo split ----
        #pragma unroll
        for (int f = 0; f < COUT / 32; ++f) {
            int flat = t + 256 * f;          // COUT rows x 8 float4
            int n    = flat >> 3;
            int kq   = flat & 7;
            int k    = kt + kq * 4;
            float4 w = *(const float4*)(W + (size_t)n * CIN + k);
            half4_t vh = to_h4(w);
            half4_t vl = residual_h4(w, vh);
            *(half4_t*)&Bh[n][kq * 4] = vh;
            *(half4_t*)&Bl[n][kq * 4] = vl;
        }
        __syncthreads();
        // ---- MFMA: one 16x16x32 consumes the whole staged k-tile ----
        half8 ah[2], alo[2];
        #pragma unroll
        for (int rt = 0; rt < 2; ++rt) {
            int row = wv * 32 + rt * 16 + l15;
            ah[rt]  = *(const half8*)&Ah[row][lk * 8];
            alo[rt] = *(const half8*)&Al[row][lk * 8];
        }
        #pragma unroll
        for (int nc = 0; nc < NCT; ++nc) {
            half8 bh = *(const half8*)&Bh[nc * 16 + l15][lk * 8];
            half8 bl = *(const half8*)&Bl[nc * 16 + l15][lk * 8];
            #pragma unroll
            for (int rt = 0; rt < 2; ++rt) {
                acc[rt][nc] = __builtin_amdgcn_mfma_f32_16x16x32_f16(ah[rt],  bh, acc[rt][nc], 0, 0, 0);
                acc[rt][nc] = __builtin_amdgcn_mfma_f32_16x16x32_f16(ah[rt],  bl, acc[rt][nc], 0, 0, 0);
                acc[rt][nc] = __builtin_amdgcn_mfma_f32_16x16x32_f16(alo[rt], bh, acc[rt][nc], 0, 0, 0);
            }
        }
        __syncthreads();
    }

    // ---- epilogue: stores + weighted per-channel stats (csum/csq alias Ah space) ----
    float* csum = (float*)&Ah[0][0];
    float* csq  = csum + COUT;
    for (int n = t; n < COUT; n += 256) { csum[n] = 0.f; csq[n] = 0.f; }
    __syncthreads();

    float tsum[NCT], tsq[NCT];
    #pragma unroll
    for (int nc = 0; nc < NCT; ++nc) { tsum[nc] = 0.f; tsq[nc] = 0.f; }

    #pragma unroll
    for (int rt = 0; rt < 2; ++rt) {
        #pragma unroll
        for (int r = 0; r < 4; ++r) {
            int row = wv * 32 + rt * 16 + lk * 4 + r;   // C/D: row=(lane>>4)*4+reg
            int pix = m0 + row;
            if (pix < NSYM) {
                float wgt = wg[row];
                #pragma unroll
                for (int nc = 0; nc < NCT; ++nc) {
                    float v = acc[rt][nc][r];
                    tsum[nc] += wgt * v;
                    tsq[nc]  += wgt * v * v;
                    out[(size_t)pix * 256 + nc * 16 + l15] = v;   // col = lane&15
                }
            }
        }
    }
    #pragma unroll
    for (int nc = 0; nc < NCT; ++nc) {
        atomicAdd(&csum[nc * 16 + l15], tsum[nc]);
        atomicAdd(&csq[nc * 16 + l15],  tsq[nc]);
    }
    __syncthreads();
    for (int n = t; n < COUT; n += 256) {
        atomicAdd(&stat_sum[n], (double)csum[n]);
        atomicAdd(&stat_sq[n],  (double)csq[n]);
    }
}

// double stats -> BN scale/shift (conv bias cancels exactly inside BatchNorm -> skipped)
__global__ void bn_finalize(const double* __restrict__ ssum, const double* __restrict__ ssq,
                            const float* __restrict__ g, const float* __restrict__ be,
                            float* __restrict__ scale, float* __restrict__ shift, int C)
{
    int c = threadIdx.x + blockIdx.x * blockDim.x;
    if (c < C) {
        double m = ssum[c] * (1.0 / NPIX);
        double v = ssq[c] * (1.0 / NPIX) - m * m;   // jnp.var, ddof=0
        float s = g[c] / sqrtf((float)v + BN_EPS);
        scale[c] = s;
        shift[c] = be[c] - (float)m * s;
    }
}

// BN3 + LeakyReLU + dot(w4) + b4 for every triangle row -> logit_tri[NSYM]
__global__ __launch_bounds__(256)
void logits_tri(const float* __restrict__ act,   // [NSYM, 256] (first 128 ch valid)
                const float* __restrict__ scale, const float* __restrict__ shift,
                const float* __restrict__ w4, const float* __restrict__ b4,
                float* __restrict__ lt)
{
    int s = blockIdx.x * 256 + threadIdx.x;
    if (s >= NSYM) return;
    const float* p = act + (size_t)s * 256;
    float acc = 0.f;
    #pragma unroll
    for (int c = 0; c < 128; c += 4) {
        float4 u  = ld4(p + c);
        float4 sc = *(const float4*)(scale + c);
        float4 sh = *(const float4*)(shift + c);
        float4 w  = *(const float4*)(w4 + c);
        acc += lrelu(fmaf(u.x, sc.x, sh.x)) * w.x;
        acc += lrelu(fmaf(u.y, sc.y, sh.y)) * w.y;
        acc += lrelu(fmaf(u.z, sc.z, sh.z)) * w.z;
        acc += lrelu(fmaf(u.w, sc.w, sh.w)) * w.w;
    }
    lt[s] = acc + b4[0];
}

// gather symmetric logits -> softmax over j -> top-K rank mask (stable tie-break)
__global__ __launch_bounds__(256)
void final_softmax_topk_sym(const float* __restrict__ lt, float* __restrict__ outp)
{
    __shared__ float sv[NV];
    __shared__ float red[256];
    const int row = blockIdx.x;                 // b*NV + i
    const int b   = row / NV;
    const int i   = row - b * NV;
    const int t   = threadIdx.x;

    float logit = -INFINITY;
    if (t < NV) {
        int jm = (i < t) ? i : t;
        int jM = (i < t) ? t : i;
        logit = lt[b * TRI + tri_base(jm) + (jM - jm)];
    }
    red[t] = logit;
    __syncthreads();
    #pragma unroll
    for (int off = 128; off > 0; off >>= 1) {
        if (t < off) red[t] = fmaxf(red[t], red[t + off]);
        __syncthreads();
    }
    float mx = red[0];
    __syncthreads();
    float e = (t < NV) ? expf(logit - mx) : 0.f;
    red[t] = e;
    __syncthreads();
    #pragma unroll
    for (int off = 128; off > 0; off >>= 1) {
        if (t < off) red[t] += red[t + off];
        __syncthreads();
    }
    float denom = red[0];
    __syncthreads();
    float val = e / denom;
    if (t < NV) sv[t] = val;
    __syncthreads();
    if (t < NV) {
        int rank = 0;
        for (int j = 0; j < NV; ++j) {
            float o = sv[j];
            rank += (o > val || (o == val && j < t)) ? 1 : 0;
        }
        outp[(size_t)row * NV + t] = (rank < KSEL) ? val : 0.f;
    }
}

extern "C" void kernel_launch(void* const* d_in, const int* in_sizes, int n_in,
                              void* d_out, int out_size, void* d_ws, size_t ws_size,
                              hipStream_t stream)
{
    (void)in_sizes; (void)n_in; (void)out_size; (void)ws_size;

    const float* x   = (const float*)d_in[0];
    const float* w0  = (const float*)d_in[1];
    const float* g0  = (const float*)d_in[3];
    const float* be0 = (const float*)d_in[4];
    const float* w1  = (const float*)d_in[5];
    const float* g1  = (const float*)d_in[7];
    const float* be1 = (const float*)d_in[8];
    const float* w2  = (const float*)d_in[9];
    const float* g2  = (const float*)d_in[11];
    const float* be2 = (const float*)d_in[12];
    const float* w3  = (const float*)d_in[13];
    const float* g3  = (const float*)d_in[15];
    const float* be3 = (const float*)d_in[16];
    const float* w4  = (const float*)d_in[17];
    const float* b4  = (const float*)d_in[18];
    // b0..b3 unused: conv bias cancels exactly in the following BatchNorm.

    char* ws = (char*)d_ws;
    // layout: [double stats 16KB][scale/shift 8KB][logit_tri 650KB][activation buffer]
    double* D    = (double*)ws;                    // 4 stages x (sum[256]|sq[256])
    float*  F    = (float*)(ws + 16384);           // 4 stages x (scale[256]|shift[256])
    float*  lt   = (float*)(ws + 16384 + 8192);
    float*  buf  = (float*)(ws + 16384 + 8192 + 655360);
    float*  outp = (float*)d_out;

    zero_stats<<<8, 256, 0, stream>>>(D);

    const int g128 = (NSYM + 127) / 128;   // 1269

    // L0: |xi-xj| -> conv0 (256->256)
    gemm_bn_mfma<256, 256, 0><<<g128, 256, 0, stream>>>(
        x, nullptr, w0, nullptr, nullptr, buf, D + 0, D + 256);
    bn_finalize<<<1, 256, 0, stream>>>(D + 0, D + 256, g0, be0, F + 0, F + 256, 256);

    // L1: BN0+LReLU -> conv1 (256->256), in-place
    gemm_bn_mfma<256, 256, 1><<<g128, 256, 0, stream>>>(
        nullptr, buf, w1, F + 0, F + 256, buf, D + 512, D + 768);
    bn_finalize<<<1, 256, 0, stream>>>(D + 512, D + 768, g1, be1, F + 512, F + 768, 256);

    // L2: BN1+LReLU -> conv2 (256->128), in-place
    gemm_bn_mfma<256, 128, 1><<<g128, 256, 0, stream>>>(
        nullptr, buf, w2, F + 512, F + 768, buf, D + 1024, D + 1280);
    bn_finalize<<<1, 256, 0, stream>>>(D + 1024, D + 1280, g2, be2, F + 1024, F + 1280, 128);

    // L3: BN2+LReLU -> conv3 (128->128), in-place
    gemm_bn_mfma<128, 128, 1><<<g128, 256, 0, stream>>>(
        nullptr, buf, w3, F + 1024, F + 1280, buf, D + 1536, D + 1792);
    bn_finalize<<<1, 256, 0, stream>>>(D + 1536, D + 1792, g3, be3, F + 1536, F + 1792, 128);

    logits_tri<<<(NSYM + 255) / 256, 256, 0, stream>>>(buf, F + 1536, F + 1792, w4, b4, lt);
    final_softmax_topk_sym<<<NB * NV, 256, 0, stream>>>(lt, outp);
}

// Round 14
// 664.917 us; speedup vs baseline: 9.3151x; 1.0306x over previous
//
#include <hip/hip_runtime.h>
#include <math.h>

#define NB 8
#define NV 201
#define ND 256
#define NPIX (NB*NV*NV)        // 323208 (full pixel count; BN normalizer)
#define TRI  (NV*(NV+1)/2)     // 20301 upper-triangle pixels per batch (i<=j)
#define NSYM (NB*TRI)          // 162408 stored rows in symmetric mode
#define KSEL 100
#define BN_EPS 1e-5f
#define SLOPE 0.01f

__device__ __forceinline__ float lrelu(float v) { return v >= 0.f ? v : SLOPE * v; }

typedef _Float16 half4_t __attribute__((ext_vector_type(4)));
typedef _Float16 half8   __attribute__((ext_vector_type(8)));
typedef float    f32x4   __attribute__((ext_vector_type(4)));

// fp16x2 split, by-value (vector elements cannot bind to C++ references — r11 lesson)
__device__ __forceinline__ half4_t to_h4(float4 v) {
    half4_t h;
    h.x = (_Float16)v.x; h.y = (_Float16)v.y;
    h.z = (_Float16)v.z; h.w = (_Float16)v.w;
    return h;
}
__device__ __forceinline__ half4_t residual_h4(float4 v, half4_t h) {
    half4_t l;
    l.x = (_Float16)(v.x - (float)h.x); l.y = (_Float16)(v.y - (float)h.y);
    l.z = (_Float16)(v.z - (float)h.z); l.w = (_Float16)(v.w - (float)h.w);
    return l;
}
__device__ __forceinline__ half8 cat8(half4_t a, half4_t b) {
    half8 r;
    r[0] = a.x; r[1] = a.y; r[2] = a.z; r[3] = a.w;
    r[4] = b.x; r[5] = b.y; r[6] = b.z; r[7] = b.w;
    return r;
}

// ---- triangle index helpers (upper triangle incl. diagonal, row-major) ----
__device__ __forceinline__ int tri_base(int i) { return i * NV - (i * (i - 1)) / 2; }
__device__ __forceinline__ void tri_decode(int s, int& b, int& i, int& j) {
    b = s / TRI;
    int t = s - b * TRI;
    float disc = (float)(403 * 403) - 8.0f * (float)t;   // (2*NV+1)^2 - 8t
    int ii = (int)((403.0f - sqrtf(disc)) * 0.5f);
    if (ii < 0) ii = 0;
    if (ii > NV - 1) ii = NV - 1;
    while (ii < NV - 1 && tri_base(ii + 1) <= t) ++ii;
    while (ii > 0 && tri_base(ii) > t) --ii;
    i = ii;
    j = t - tri_base(ii) + ii;
}

__device__ __forceinline__ float4 ld4(const float* p) { return *(const float4*)p; }

__global__ void zero_stats(double* p) { p[blockIdx.x * 256 + threadIdx.x] = 0.0; }

// MFMA GEMM, fp16x2-split (fp32-faithful): C = Ah*Bh + Ah*Bl + Al*Bh, fp32 acc.
// r13 restructure: A operands loaded PER-WAVE straight from global (L2/L3-resident)
// and split in registers — no A staging in LDS. Only B (weights, hi/lo) is staged:
// LDS 41KB (COUT=256) -> 3 blocks/CU, 21KB (COUT=128) -> 7 blocks/CU (was 62KB/2).
// 2x2 wave tiling (wave = 64 rows x COUT/2 cols): B LDS reads 32->16 b128/wave/ktile.
// Numerics identical to the r13-verified kernel (same 3-term split, same k-order for
// A and B => permutation-invariant). SINGLE-OWNER rows -> in-place safe.
template<int CIN, int COUT, int MODE>
__global__ __launch_bounds__(256)
void gemm_bn_mfma(const float* xin,               // MODE 0 source ([8,201,256] fp32)
                  const float* in,                // MODE 1 source (element stride 256)
                  const float* __restrict__ W,    // [COUT, CIN]
                  const float* __restrict__ scale,
                  const float* __restrict__ shift,
                  float* out,                     // element stride 256 (may alias `in`)
                  double* __restrict__ stat_sum,
                  double* __restrict__ stat_sq)
{
    constexpr int BM  = 128;
    constexpr int BK  = 32;
    constexpr int PAD = 40;          // 80B rows: 16B-aligned b128 reads, 2-way banks (free)
    constexpr int NCW = COUT / 32;   // col-tiles per wave (8 or 4)
    __shared__ __align__(16) _Float16 Bh[COUT][PAD];
    __shared__ __align__(16) _Float16 Bl[COUT][PAD];
    __shared__ float wg[BM];                      // stats weight (1 diag / 2 off-diag)
    __shared__ int   rbi[(MODE == 0) ? BM : 1];
    __shared__ int   rbj[(MODE == 0) ? BM : 1];

    const int t    = threadIdx.x;
    const int lane = t & 63;
    const int wv   = t >> 6;
    const int wm   = wv >> 1;        // row half: rows [wm*64, wm*64+64)
    const int wn   = wv & 1;         // col half: cols [wn*COUT/2, +COUT/2)
    const int l15  = lane & 15;
    const int lk   = lane >> 4;      // k-group / C-row-group
    const int m0   = blockIdx.x * BM;

    for (int m = t; m < BM; m += 256) {
        int pix = m0 + m;
        int b, i, j;
        if (pix < NSYM) {
            tri_decode(pix, b, i, j);
            wg[m] = (i == j) ? 1.f : 2.f;
            if constexpr (MODE == 0) { rbi[m] = b * NV + i; rbj[m] = b * NV + j; }
        } else {
            wg[m] = 0.f;
            if constexpr (MODE == 0) { rbi[m] = 0; rbj[m] = 0; }
        }
    }

    f32x4 acc[4][NCW];
    #pragma unroll
    for (int rt = 0; rt < 4; ++rt)
        #pragma unroll
        for (int nc = 0; nc < NCW; ++nc) {
            acc[rt][nc][0] = 0.f; acc[rt][nc][1] = 0.f;
            acc[rt][nc][2] = 0.f; acc[rt][nc][3] = 0.f;
        }

    for (int kt = 0; kt < CIN; kt += BK) {
        // ---- stage B tile (hi/lo) into LDS ----
        #pragma unroll
        for (int f = 0; f < COUT / 32; ++f) {
            int flat = t + 256 * f;          // COUT rows x 8 float4
            int n    = flat >> 3;
            int kq   = flat & 7;
            int k    = kt + kq * 4;
            float4 w = *(const float4*)(W + (size_t)n * CIN + k);
            half4_t vh = to_h4(w);
            half4_t vl = residual_h4(w, vh);
            *(half4_t*)&Bh[n][kq * 4] = vh;
            *(half4_t*)&Bl[n][kq * 4] = vl;
        }
        __syncthreads();   // also covers wg/rbi/rbj on first iteration

        // ---- A fragments straight from global, split in registers ----
        float4 sc0, sc1, sh0, sh1;
        if constexpr (MODE == 1) {
            sc0 = ld4(scale + kt + lk * 8); sc1 = ld4(scale + kt + lk * 8 + 4);
            sh0 = ld4(shift + kt + lk * 8); sh1 = ld4(shift + kt + lk * 8 + 4);
        }
        half8 ah[4], alo[4];
        #pragma unroll
        for (int rt = 0; rt < 4; ++rt) {
            int m   = wm * 64 + rt * 16 + l15;
            int pix = m0 + m;
            float4 v0 = make_float4(0.f, 0.f, 0.f, 0.f);
            float4 v1 = v0;
            if (pix < NSYM) {
                if constexpr (MODE == 0) {
                    const float* pi = xin + (size_t)rbi[m] * ND + kt + lk * 8;
                    const float* pj = xin + (size_t)rbj[m] * ND + kt + lk * 8;
                    float4 xi0 = ld4(pi), xi1 = ld4(pi + 4);
                    float4 xj0 = ld4(pj), xj1 = ld4(pj + 4);
                    v0 = make_float4(fabsf(xi0.x - xj0.x), fabsf(xi0.y - xj0.y),
                                     fabsf(xi0.z - xj0.z), fabsf(xi0.w - xj0.w));
                    v1 = make_float4(fabsf(xi1.x - xj1.x), fabsf(xi1.y - xj1.y),
                                     fabsf(xi1.z - xj1.z), fabsf(xi1.w - xj1.w));
                } else {
                    const float* p = in + (size_t)pix * 256 + kt + lk * 8;
                    float4 u0 = ld4(p), u1 = ld4(p + 4);
                    v0.x = lrelu(fmaf(u0.x, sc0.x, sh0.x));
                    v0.y = lrelu(fmaf(u0.y, sc0.y, sh0.y));
                    v0.z = lrelu(fmaf(u0.z, sc0.z, sh0.z));
                    v0.w = lrelu(fmaf(u0.w, sc0.w, sh0.w));
                    v1.x = lrelu(fmaf(u1.x, sc1.x, sh1.x));
                    v1.y = lrelu(fmaf(u1.y, sc1.y, sh1.y));
                    v1.z = lrelu(fmaf(u1.z, sc1.z, sh1.z));
                    v1.w = lrelu(fmaf(u1.w, sc1.w, sh1.w));
                }
            }
            half4_t h0 = to_h4(v0), h1 = to_h4(v1);
            half4_t l0 = residual_h4(v0, h0), l1 = residual_h4(v1, h1);
            ah[rt]  = cat8(h0, h1);
            alo[rt] = cat8(l0, l1);
        }

        // ---- MFMA over this wave's col half ----
        #pragma unroll
        for (int nc = 0; nc < NCW; ++nc) {
            int ctrow = (wn * NCW + nc) * 16 + l15;
            half8 bh = *(const half8*)&Bh[ctrow][lk * 8];
            half8 bl = *(const half8*)&Bl[ctrow][lk * 8];
            #pragma unroll
            for (int rt = 0; rt < 4; ++rt) {
                acc[rt][nc] = __builtin_amdgcn_mfma_f32_16x16x32_f16(ah[rt],  bh, acc[rt][nc], 0, 0, 0);
                acc[rt][nc] = __builtin_amdgcn_mfma_f32_16x16x32_f16(ah[rt],  bl, acc[rt][nc], 0, 0, 0);
                acc[rt][nc] = __builtin_amdgcn_mfma_f32_16x16x32_f16(alo[rt], bh, acc[rt][nc], 0, 0, 0);
            }
        }
        __syncthreads();   // B tile consumed; safe to restage
    }

    // ---- epilogue: stores + weighted per-channel stats (csum/csq alias Bh space) ----
    float* csum = (float*)&Bh[0][0];
    float* csq  = csum + COUT;
    for (int n = t; n < COUT; n += 256) { csum[n] = 0.f; csq[n] = 0.f; }
    __syncthreads();

    float tsum[NCW], tsq[NCW];
    #pragma unroll
    for (int nc = 0; nc < NCW; ++nc) { tsum[nc] = 0.f; tsq[nc] = 0.f; }

    #pragma unroll
    for (int rt = 0; rt < 4; ++rt) {
        #pragma unroll
        for (int r = 0; r < 4; ++r) {
            int row = wm * 64 + rt * 16 + lk * 4 + r;   // C/D: row=(lane>>4)*4+reg
            int pix = m0 + row;
            if (pix < NSYM) {
                float wgt = wg[row];
                #pragma unroll
                for (int nc = 0; nc < NCW; ++nc) {
                    float v = acc[rt][nc][r];
                    tsum[nc] += wgt * v;
                    tsq[nc]  += wgt * v * v;
                    out[(size_t)pix * 256 + wn * (COUT / 2) + nc * 16 + l15] = v;
                }
            }
        }
    }
    #pragma unroll
    for (int nc = 0; nc < NCW; ++nc) {
        int col = wn * (COUT / 2) + nc * 16 + l15;
        atomicAdd(&csum[col], tsum[nc]);
        atomicAdd(&csq[col],  tsq[nc]);
    }
    __syncthreads();
    for (int n = t; n < COUT; n += 256) {
        atomicAdd(&stat_sum[n], (double)csum[n]);
        atomicAdd(&stat_sq[n],  (double)csq[n]);
    }
}

// double stats -> BN scale/shift (conv bias cancels exactly inside BatchNorm -> skipped)
__global__ void bn_finalize(const double* __restrict__ ssum, const double* __restrict__ ssq,
                            const float* __restrict__ g, const float* __restrict__ be,
                            float* __restrict__ scale, float* __restrict__ shift, int C)
{
    int c = threadIdx.x + blockIdx.x * blockDim.x;
    if (c < C) {
        double m = ssum[c] * (1.0 / NPIX);
        double v = ssq[c] * (1.0 / NPIX) - m * m;   // jnp.var, ddof=0
        float s = g[c] / sqrtf((float)v + BN_EPS);
        scale[c] = s;
        shift[c] = be[c] - (float)m * s;
    }
}

// BN3 + LeakyReLU + dot(w4) + b4 for every triangle row -> logit_tri[NSYM]
__global__ __launch_bounds__(256)
void logits_tri(const float* __restrict__ act,   // [NSYM, 256] (first 128 ch valid)
                const float* __restrict__ scale, const float* __restrict__ shift,
                const float* __restrict__ w4, const float* __restrict__ b4,
                float* __restrict__ lt)
{
    int s = blockIdx.x * 256 + threadIdx.x;
    if (s >= NSYM) return;
    const float* p = act + (size_t)s * 256;
    float acc = 0.f;
    #pragma unroll
    for (int c = 0; c < 128; c += 4) {
        float4 u  = ld4(p + c);
        float4 sc = *(const float4*)(scale + c);
        float4 sh = *(const float4*)(shift + c);
        float4 w  = *(const float4*)(w4 + c);
        acc += lrelu(fmaf(u.x, sc.x, sh.x)) * w.x;
        acc += lrelu(fmaf(u.y, sc.y, sh.y)) * w.y;
        acc += lrelu(fmaf(u.z, sc.z, sh.z)) * w.z;
        acc += lrelu(fmaf(u.w, sc.w, sh.w)) * w.w;
    }
    lt[s] = acc + b4[0];
}

// gather symmetric logits -> softmax over j -> top-K rank mask (stable tie-break)
__global__ __launch_bounds__(256)
void final_softmax_topk_sym(const float* __restrict__ lt, float* __restrict__ outp)
{
    __shared__ float sv[NV];
    __shared__ float red[256];
    const int row = blockIdx.x;                 // b*NV + i
    const int b   = row / NV;
    const int i   = row - b * NV;
    const int t   = threadIdx.x;

    float logit = -INFINITY;
    if (t < NV) {
        int jm = (i < t) ? i : t;
        int jM = (i < t) ? t : i;
        logit = lt[b * TRI + tri_base(jm) + (jM - jm)];
    }
    red[t] = logit;
    __syncthreads();
    #pragma unroll
    for (int off = 128; off > 0; off >>= 1) {
        if (t < off) red[t] = fmaxf(red[t], red[t + off]);
        __syncthreads();
    }
    float mx = red[0];
    __syncthreads();
    float e = (t < NV) ? expf(logit - mx) : 0.f;
    red[t] = e;
    __syncthreads();
    #pragma unroll
    for (int off = 128; off > 0; off >>= 1) {
        if (t < off) red[t] += red[t + off];
        __syncthreads();
    }
    float denom = red[0];
    __syncthreads();
    float val = e / denom;
    if (t < NV) sv[t] = val;
    __syncthreads();
    if (t < NV) {
        int rank = 0;
        for (int j = 0; j < NV; ++j) {
            float o = sv[j];
            rank += (o > val || (o == val && j < t)) ? 1 : 0;
        }
        outp[(size_t)row * NV + t] = (rank < KSEL) ? val : 0.f;
    }
}

extern "C" void kernel_launch(void* const* d_in, const int* in_sizes, int n_in,
                              void* d_out, int out_size, void* d_ws, size_t ws_size,
                              hipStream_t stream)
{
    (void)in_sizes; (void)n_in; (void)out_size; (void)ws_size;

    const float* x   = (const float*)d_in[0];
    const float* w0  = (const float*)d_in[1];
    const float* g0  = (const float*)d_in[3];
    const float* be0 = (const float*)d_in[4];
    const float* w1  = (const float*)d_in[5];
    const float* g1  = (const float*)d_in[7];
    const float* be1 = (const float*)d_in[8];
    const float* w2  = (const float*)d_in[9];
    const float* g2  = (const float*)d_in[11];
    const float* be2 = (const float*)d_in[12];
    const float* w3  = (const float*)d_in[13];
    const float* g3  = (const float*)d_in[15];
    const float* be3 = (const float*)d_in[16];
    const float* w4  = (const float*)d_in[17];
    const float* b4  = (const float*)d_in[18];
    // b0..b3 unused: conv bias cancels exactly in the following BatchNorm.

    char* ws = (char*)d_ws;
    // layout: [double stats 16KB][scale/shift 8KB][logit_tri 650KB][activation buffer]
    double* D    = (double*)ws;                    // 4 stages x (sum[256]|sq[256])
    float*  F    = (float*)(ws + 16384);           // 4 stages x (scale[256]|shift[256])
    float*  lt   = (float*)(ws + 16384 + 8192);
    float*  buf  = (float*)(ws + 16384 + 8192 + 655360);
    float*  outp = (float*)d_out;

    zero_stats<<<8, 256, 0, stream>>>(D);

    const int g128 = (NSYM + 127) / 128;   // 1269

    // L0: |xi-xj| -> conv0 (256->256)
    gemm_bn_mfma<256, 256, 0><<<g128, 256, 0, stream>>>(
        x, nullptr, w0, nullptr, nullptr, buf, D + 0, D + 256);
    bn_finalize<<<1, 256, 0, stream>>>(D + 0, D + 256, g0, be0, F + 0, F + 256, 256);

    // L1: BN0+LReLU -> conv1 (256->256), in-place
    gemm_bn_mfma<256, 256, 1><<<g128, 256, 0, stream>>>(
        nullptr, buf, w1, F + 0, F + 256, buf, D + 512, D + 768);
    bn_finalize<<<1, 256, 0, stream>>>(D + 512, D + 768, g1, be1, F + 512, F + 768, 256);

    // L2: BN1+LReLU -> conv2 (256->128), in-place
    gemm_bn_mfma<256, 128, 1><<<g128, 256, 0, stream>>>(
        nullptr, buf, w2, F + 512, F + 768, buf, D + 1024, D + 1280);
    bn_finalize<<<1, 256, 0, stream>>>(D + 1024, D + 1280, g2, be2, F + 1024, F + 1280, 128);

    // L3: BN2+LReLU -> conv3 (128->128), in-place
    gemm_bn_mfma<128, 128, 1><<<g128, 256, 0, stream>>>(
        nullptr, buf, w3, F + 1024, F + 1280, buf, D + 1536, D + 1792);
    bn_finalize<<<1, 256, 0, stream>>>(D + 1536, D + 1792, g3, be3, F + 1536, F + 1792, 128);

    logits_tri<<<(NSYM + 255) / 256, 256, 0, stream>>>(buf, F + 1536, F + 1792, w4, b4, lt);
    final_softmax_topk_sym<<<NB * NV, 256, 0, stream>>>(lt, outp);
}